// Round 1
// baseline (219.383 us; speedup 1.0000x reference)
//
#include <hip/hip_runtime.h>
#include <hip/hip_bf16.h>

#define L 512
#define CS 256
#define CZ 128
#define LN_EPS 1e-5f

typedef _Float16 f16_t;
typedef f16_t f16x8 __attribute__((ext_vector_type(8)));
typedef float f32x4 __attribute__((ext_vector_type(4)));

// ---- Kernel PREP -----------------------------------------------------------
// Per-block (i = blockIdx.x): embed + LN -> s_out, u2 (CHUNK-MAJOR f16:
// u2[c>>3][i][c&7]), zrow = u@W1 + b, zcol = u@W2.
// Spare duties: blocks 0..127 build w3c (chunk-major W3^T f16), blocks
// 128..391 build tab[cp*66+rp] = Ecp[cp] + Erp[rp].
__global__ __launch_bounds__(256) void k_prep(
    const int* __restrict__ seq, const int* __restrict__ cid,
    const int* __restrict__ ridx,
    const float* __restrict__ Eaa, const float* __restrict__ Epos,
    const float* __restrict__ Ech, const float* __restrict__ lnw,
    const float* __restrict__ lnb, const float* __restrict__ Wp,
    const float* __restrict__ bp, const float* __restrict__ Ecp,
    const float* __restrict__ Erp,
    float* __restrict__ s_out, f16_t* __restrict__ u2,
    float* __restrict__ zrow, float* __restrict__ zcol,
    f16_t* __restrict__ w3c, float* __restrict__ tab)
{
    __shared__ float su[CS];
    __shared__ float red[8];
    const int i = blockIdx.x;
    const int c = threadIdx.x;

    if (i < 128) {
        w3c[(c >> 3) * (CZ * 8) + i * 8 + (c & 7)] = (f16_t)Wp[(2 * CS + c) * CZ + i];
    } else if (i < 128 + 264) {
        const int b2 = i - 128;
        if (c < CZ)
            tab[b2 * CZ + c] = Ecp[(b2 / 66) * CZ + c] + Erp[(b2 % 66) * CZ + c];
    }

    const int sq = seq[i], ri = ridx[i], ci = cid[i];
    const float v = Eaa[sq * CS + c] + Epos[ri * CS + c] + Ech[ci * CS + c];
    s_out[i * CS + c] = v;

    float s1 = v, s2 = v * v;
    #pragma unroll
    for (int o = 32; o > 0; o >>= 1) {
        s1 += __shfl_down(s1, o, 64);
        s2 += __shfl_down(s2, o, 64);
    }
    const int wv = c >> 6, lane = c & 63;
    if (lane == 0) { red[wv * 2] = s1; red[wv * 2 + 1] = s2; }
    __syncthreads();
    const float S  = red[0] + red[2] + red[4] + red[6];
    const float SS = red[1] + red[3] + red[5] + red[7];
    const float mu  = S * (1.0f / CS);
    const float var = SS * (1.0f / CS) - mu * mu;
    const float rs  = rsqrtf(var + LN_EPS);
    const float u   = (v - mu) * rs * lnw[c] + lnb[c];
    u2[(c >> 3) * (L * 8) + i * 8 + (c & 7)] = (f16_t)u;
    su[c] = u;
    __syncthreads();

    const int z = c & 127;
    const int half = c >> 7;  // 0 -> zrow(W1), 1 -> zcol(W2)
    const float* W = Wp + half * CS * CZ + z;
    float a0 = 0, a1 = 0, a2 = 0, a3 = 0;
    #pragma unroll 8
    for (int cc = 0; cc < CS; cc += 4) {
        a0 += su[cc + 0] * W[(cc + 0) * CZ];
        a1 += su[cc + 1] * W[(cc + 1) * CZ];
        a2 += su[cc + 2] * W[(cc + 2) * CZ];
        a3 += su[cc + 3] * W[(cc + 3) * CZ];
    }
    const float acc = (a0 + a1) + (a2 + a3);
    if (half) zcol[i * CZ + z] = acc;
    else      zrow[i * CZ + z] = acc + bp[z];
}

// ---- Kernel PAIR (v2: zero-LDS, all-register) ------------------------------
// Old structure: 8 z-segment waves each re-read the same u_i/u_j from LDS
// (1.05M ds_read_b128 total = 49K cyc/CU, as large as the 52K-cyc store
// floor) and recomputed ui*uj 8x redundantly. New structure:
//   block = 512 thr, tile 8i x 16j x 128z, grid (32,64)
//   wave w: z-seg = (w&3)*32 (two 16z MFMA tiles), i-half = w>>2 (4 i's)
// All operands hoisted to VGPRs directly from L2 (u2 256KB + w3c 64KB are
// cache-resident; no HBM reads): A-slice 64v, Uj 32v, per-i-pair Ua/Ub 64v.
// No LDS, no barrier. i's processed in pairs -> 4 independent MFMA chains
// per wave (8/SIMD at 2 waves/SIMD) to cover MFMA latency.
// VGPR ~235 -> 1 block/CU; fine since stores are fire-and-forget and every
// load is hoisted ahead of its MFMA chain.
__global__ __launch_bounds__(512, 2) void k_pair(
    const f16_t* __restrict__ u2, const f16_t* __restrict__ w3c,
    const float* __restrict__ zrow, const float* __restrict__ zcol,
    const float* __restrict__ tab,
    const int* __restrict__ cid, const int* __restrict__ ridx,
    float* __restrict__ zout)
{
    const int t = threadIdx.x;
    const int lane = t & 63, wave = t >> 6;
    const int m = lane & 15, q = lane >> 4;
    const int j0 = blockIdx.x * 16, i0 = blockIdx.y * 8;
    const int zsg = (wave & 3) * 32;          // wave's 32-z segment
    const int ibase = i0 + (wave >> 2) * 4;   // wave's 4 i's
    const int zq0 = zsg + q * 4;              // z-tile 0: lane's 4 z's
    const int zq1 = zsg + 16 + q * 4;         // z-tile 1

    const f16x8* pu = (const f16x8*)u2;       // [32 chunks][512 rows]
    const f16x8* pw = (const f16x8*)w3c;      // [32 chunks][128 z]

    // hoisted A (W3^T, 32z x 256c slice) and Uj (16 j rows), straight from L2
    f16x8 A0[8], A1[8], Uj[8];
    #pragma unroll
    for (int k32 = 0; k32 < 8; ++k32) {
        const int cb = k32 * 4 + q;           // c-chunk: c = cb*8 + e
        A0[k32] = pw[cb * CZ + zsg + m];
        A1[k32] = pw[cb * CZ + zsg + 16 + m];
        Uj[k32] = pu[cb * L + j0 + m];
    }
    const int jm = j0 + m;
    const int cj = cid[jm], rj = ridx[jm];
    const f32x4 ZC0 = *(const f32x4*)&zcol[jm * CZ + zq0];
    const f32x4 ZC1 = *(const f32x4*)&zcol[jm * CZ + zq1];

    for (int ip = 0; ip < 2; ++ip) {
        const int ia = ibase + ip * 2, ib = ia + 1;

        // per-i operand rows (4-way-broadcast reads, L2-resident)
        f16x8 Ua[8], Ub[8];
        #pragma unroll
        for (int k32 = 0; k32 < 8; ++k32) {
            const int cb = k32 * 4 + q;
            Ua[k32] = pu[cb * L + ia];
            Ub[k32] = pu[cb * L + ib];
        }

        // epilogue operands (independent of the MFMA chains; issue early)
        const int ca = cid[ia], ra = ridx[ia];
        const int cb2 = cid[ib], rb2 = ridx[ib];
        int d;
        d = ra - rj;  d = d < -32 ? -32 : (d > 32 ? 32 : d);
        const int xa = ((ca * 2 + cj) * 66) + ((ca == cj) ? (d + 32) : 65);
        d = rb2 - rj; d = d < -32 ? -32 : (d > 32 ? 32 : d);
        const int xb = ((cb2 * 2 + cj) * 66) + ((cb2 == cj) ? (d + 32) : 65);
        f32x4 zra0 = *(const f32x4*)&zrow[ia * CZ + zq0];
        f32x4 zra1 = *(const f32x4*)&zrow[ia * CZ + zq1];
        f32x4 zrb0 = *(const f32x4*)&zrow[ib * CZ + zq0];
        f32x4 zrb1 = *(const f32x4*)&zrow[ib * CZ + zq1];
        f32x4 ta0 = *(const f32x4*)&tab[xa * CZ + zq0];
        f32x4 ta1 = *(const f32x4*)&tab[xa * CZ + zq1];
        f32x4 tb0 = *(const f32x4*)&tab[xb * CZ + zq0];
        f32x4 tb1 = *(const f32x4*)&tab[xb * CZ + zq1];

        f32x4 aa0 = {0,0,0,0}, aa1 = {0,0,0,0};
        f32x4 ab0 = {0,0,0,0}, ab1 = {0,0,0,0};
        #pragma unroll
        for (int k32 = 0; k32 < 8; ++k32) {
            const f16x8 Ba = Ua[k32] * Uj[k32];   // ui (x) uj, shared by both z-tiles
            const f16x8 Bb = Ub[k32] * Uj[k32];
            aa0 = __builtin_amdgcn_mfma_f32_16x16x32_f16(A0[k32], Ba, aa0, 0, 0, 0);
            aa1 = __builtin_amdgcn_mfma_f32_16x16x32_f16(A1[k32], Ba, aa1, 0, 0, 0);
            ab0 = __builtin_amdgcn_mfma_f32_16x16x32_f16(A0[k32], Bb, ab0, 0, 0, 0);
            ab1 = __builtin_amdgcn_mfma_f32_16x16x32_f16(A1[k32], Bb, ab1, 0, 0, 0);
        }

        float* r_a = zout + ((size_t)ia * L + jm) * CZ;
        float* r_b = zout + ((size_t)ib * L + jm) * CZ;
        f32x4 o;
        o = aa0 + zra0 + ZC0 + ta0; *(f32x4*)(r_a + zq0) = o;
        o = aa1 + zra1 + ZC1 + ta1; *(f32x4*)(r_a + zq1) = o;
        o = ab0 + zrb0 + ZC0 + tb0; *(f32x4*)(r_b + zq0) = o;
        o = ab1 + zrb1 + ZC1 + tb1; *(f32x4*)(r_b + zq1) = o;
    }
}

extern "C" void kernel_launch(void* const* d_in, const int* in_sizes, int n_in,
                              void* d_out, int out_size, void* d_ws, size_t ws_size,
                              hipStream_t stream) {
    const int*   seq  = (const int*)d_in[0];
    const int*   cid  = (const int*)d_in[1];
    const int*   ridx = (const int*)d_in[2];
    const float* Eaa  = (const float*)d_in[3];
    const float* Epos = (const float*)d_in[4];
    const float* Ech  = (const float*)d_in[5];
    const float* Ecp  = (const float*)d_in[6];
    const float* Erp  = (const float*)d_in[7];
    const float* Wp   = (const float*)d_in[8];
    const float* bp   = (const float*)d_in[9];
    const float* lnw  = (const float*)d_in[10];
    const float* lnb  = (const float*)d_in[11];

    float* out   = (float*)d_out;
    float* s_out = out;
    float* zout  = out + L * CS;

    char* ws = (char*)d_ws;
    f16_t* u2   = (f16_t*)ws;                 // 256 KB, chunk-major
    f16_t* w3c  = (f16_t*)(ws + 262144);      // 64 KB, chunk-major
    float* zrow = (float*)(ws + 327680);      // 256 KB
    float* zcol = (float*)(ws + 589824);      // 256 KB
    float* tab  = (float*)(ws + 851968);      // 132 KB

    hipLaunchKernelGGL(k_prep, dim3(L), dim3(256), 0, stream,
                       seq, cid, ridx, Eaa, Epos, Ech, lnw, lnb, Wp, bp,
                       Ecp, Erp, s_out, u2, zrow, zcol, w3c, tab);
    hipLaunchKernelGGL(k_pair, dim3(32, 64), dim3(512), 0, stream,
                       u2, w3c, zrow, zcol, tab, cid, ridx, zout);
}

// Round 2
// 193.827 us; speedup vs baseline: 1.1318x; 1.1318x over previous
//
#include <hip/hip_runtime.h>
#include <hip/hip_bf16.h>

#define L 512
#define CS 256
#define CZ 128
#define LN_EPS 1e-5f

typedef _Float16 f16_t;
typedef f16_t f16x8 __attribute__((ext_vector_type(8)));
typedef float f32x4 __attribute__((ext_vector_type(4)));

// ---- Kernel PREP -----------------------------------------------------------
// Per-block (i = blockIdx.x): embed + LN -> s_out, u2 (CHUNK-MAJOR f16:
// u2[c>>3][i][c&7]), zrow = u@W1 + b, zcol = u@W2.
// Spare duties: blocks 0..127 build w3c (chunk-major W3^T f16), blocks
// 128..391 build tab[cp*66+rp] = Ecp[cp] + Erp[rp].
__global__ __launch_bounds__(256) void k_prep(
    const int* __restrict__ seq, const int* __restrict__ cid,
    const int* __restrict__ ridx,
    const float* __restrict__ Eaa, const float* __restrict__ Epos,
    const float* __restrict__ Ech, const float* __restrict__ lnw,
    const float* __restrict__ lnb, const float* __restrict__ Wp,
    const float* __restrict__ bp, const float* __restrict__ Ecp,
    const float* __restrict__ Erp,
    float* __restrict__ s_out, f16_t* __restrict__ u2,
    float* __restrict__ zrow, float* __restrict__ zcol,
    f16_t* __restrict__ w3c, float* __restrict__ tab)
{
    __shared__ float su[CS];
    __shared__ float red[8];
    const int i = blockIdx.x;
    const int c = threadIdx.x;

    if (i < 128) {
        w3c[(c >> 3) * (CZ * 8) + i * 8 + (c & 7)] = (f16_t)Wp[(2 * CS + c) * CZ + i];
    } else if (i < 128 + 264) {
        const int b2 = i - 128;
        if (c < CZ)
            tab[b2 * CZ + c] = Ecp[(b2 / 66) * CZ + c] + Erp[(b2 % 66) * CZ + c];
    }

    const int sq = seq[i], ri = ridx[i], ci = cid[i];
    const float v = Eaa[sq * CS + c] + Epos[ri * CS + c] + Ech[ci * CS + c];
    s_out[i * CS + c] = v;

    float s1 = v, s2 = v * v;
    #pragma unroll
    for (int o = 32; o > 0; o >>= 1) {
        s1 += __shfl_down(s1, o, 64);
        s2 += __shfl_down(s2, o, 64);
    }
    const int wv = c >> 6, lane = c & 63;
    if (lane == 0) { red[wv * 2] = s1; red[wv * 2 + 1] = s2; }
    __syncthreads();
    const float S  = red[0] + red[2] + red[4] + red[6];
    const float SS = red[1] + red[3] + red[5] + red[7];
    const float mu  = S * (1.0f / CS);
    const float var = SS * (1.0f / CS) - mu * mu;
    const float rs  = rsqrtf(var + LN_EPS);
    const float u   = (v - mu) * rs * lnw[c] + lnb[c];
    u2[(c >> 3) * (L * 8) + i * 8 + (c & 7)] = (f16_t)u;
    su[c] = u;
    __syncthreads();

    const int z = c & 127;
    const int half = c >> 7;  // 0 -> zrow(W1), 1 -> zcol(W2)
    const float* W = Wp + half * CS * CZ + z;
    float a0 = 0, a1 = 0, a2 = 0, a3 = 0;
    #pragma unroll 8
    for (int cc = 0; cc < CS; cc += 4) {
        a0 += su[cc + 0] * W[(cc + 0) * CZ];
        a1 += su[cc + 1] * W[(cc + 1) * CZ];
        a2 += su[cc + 2] * W[(cc + 2) * CZ];
        a3 += su[cc + 3] * W[(cc + 3) * CZ];
    }
    const float acc = (a0 + a1) + (a2 + a3);
    if (half) zcol[i * CZ + z] = acc;
    else      zrow[i * CZ + z] = acc + bp[z];
}

// ---- Kernel PAIR (v3: LDS staging, low-redundancy tiling) ------------------
// R0 failure: 8 z-waves re-read the same u tiles -> 4096 ds_read_b128/CU =
// 49K cyc, equal to the 52K-cyc store floor. R1 failure: compiler sank the
// hoisted global loads (VGPR=76) -> L2-latency-bound, MfmaUtil 8%.
// v3: block tile 8i x 32j x 128z, 8 waves = 2ih x 2jh x 2zh; each wave owns
// 4i x 16j x 64z (4 z-tiles). Per k32 chunk: 1 uj ds_read + 4 ui broadcast
// + 4 A-loads (L2, in-loop: small live set, pipelineable) -> 16 MFMAs.
// ds:MFMA = 1:3.2 -> ~15K ds-cyc/CU; MFMA issue ~5K; VALU ~3K; all hidden
// under the 52K-cyc store floor. u_i (x) u_j computed once per 64z (2x
// redundancy vs R0's 8x). acc 64 + operands ~80 VGPR -> ~150, fits (512,2)
// with zero spill and nothing for the allocator to sink.
// LDS layout identical to R0 (measured BANK_CONFLICT = 0).
__global__ __launch_bounds__(512, 2) void k_pair(
    const f16_t* __restrict__ u2, const f16_t* __restrict__ w3c,
    const float* __restrict__ zrow, const float* __restrict__ zcol,
    const float* __restrict__ tab,
    const int* __restrict__ cid, const int* __restrict__ ridx,
    float* __restrict__ zout)
{
    __shared__ f16_t lds[(1024 + 256) * 8];  // u_j tile (16KB) + u_i tile (4KB)
    f16x8* lj = (f16x8*)lds;
    f16x8* li = ((f16x8*)lds) + 1024;

    const int t = threadIdx.x;
    const int lane = t & 63, wave = t >> 6;
    const int m = lane & 15, q = lane >> 4;
    const int j0 = blockIdx.x * 32, i0 = blockIdx.y * 8;
    const int jh = wave & 1;          // j-half: 16 j's
    const int ih = (wave >> 1) & 1;   // i-half: 4 i's
    const int zh = wave >> 2;         // z-half: 64 z's (4 tiles of 16)
    const int jm = j0 + jh * 16 + m;
    const int ib = ih * 4;            // local i base
    const int zb = zh * 64;

    const f16x8* pu = (const f16x8*)u2;      // [32 chunks][512 rows]
    const f16x8* pw = (const f16x8*)w3c;     // [32 chunks][128 z]

    // stage LDS tiles (contiguous src + dst; R0-verified conflict-free)
    if (t < 256) li[t] = pu[(t >> 3) * L + i0 + (t & 7)];   // t = ch*8 + ii
    #pragma unroll
    for (int rep = 0; rep < 2; ++rep) {
        const int un = rep * 512 + t;                       // un = ch*32 + jj
        lj[un] = pu[(un >> 5) * L + j0 + (un & 31)];
    }
    __syncthreads();

    f32x4 acc[4][4];  // [ii][zt]
    #pragma unroll
    for (int ii = 0; ii < 4; ++ii)
        #pragma unroll
        for (int zt = 0; zt < 4; ++zt)
            acc[ii][zt] = (f32x4){0.f, 0.f, 0.f, 0.f};

    #pragma unroll
    for (int k32 = 0; k32 < 8; ++k32) {
        const int cb = k32 * 4 + q;               // c-chunk index
        f16x8 Az[4];                              // A = W3^T slice, from L2
        #pragma unroll
        for (int zt = 0; zt < 4; ++zt)
            Az[zt] = pw[cb * CZ + zb + zt * 16 + m];
        const f16x8 ujv = lj[cb * 32 + jh * 16 + m];   // conflict-free b128
        #pragma unroll
        for (int ii = 0; ii < 4; ++ii) {
            const f16x8 B = li[cb * 8 + ib + ii] * ujv; // bcast read + 4 v_pk
            #pragma unroll
            for (int zt = 0; zt < 4; ++zt)
                acc[ii][zt] = __builtin_amdgcn_mfma_f32_16x16x32_f16(
                    Az[zt], B, acc[ii][zt], 0, 0, 0);
        }
    }

    // epilogue: z = zb + zt*16 + q*4 + r, j = jm  (R0-verified D mapping)
    const int cj = cid[jm], rj = ridx[jm];
    f32x4 ZC[4];
    #pragma unroll
    for (int zt = 0; zt < 4; ++zt)
        ZC[zt] = *(const f32x4*)&zcol[jm * CZ + zb + zt * 16 + q * 4];

    #pragma unroll
    for (int ii = 0; ii < 4; ++ii) {
        const int i = i0 + ib + ii;
        const int ci = cid[i], ri = ridx[i];
        int d = ri - rj; d = d < -32 ? -32 : (d > 32 ? 32 : d);
        const int x = ((ci * 2 + cj) * 66) + ((ci == cj) ? (d + 32) : 65);
        float* r_o = zout + ((size_t)i * L + jm) * CZ;
        #pragma unroll
        for (int zt = 0; zt < 4; ++zt) {
            const int zo = zb + zt * 16 + q * 4;
            const f32x4 zr = *(const f32x4*)&zrow[i * CZ + zo];
            const f32x4 tb = *(const f32x4*)&tab[x * CZ + zo];
            const f32x4 o = acc[ii][zt] + zr + ZC[zt] + tb;
            *(f32x4*)(r_o + zo) = o;
        }
    }
}

extern "C" void kernel_launch(void* const* d_in, const int* in_sizes, int n_in,
                              void* d_out, int out_size, void* d_ws, size_t ws_size,
                              hipStream_t stream) {
    const int*   seq  = (const int*)d_in[0];
    const int*   cid  = (const int*)d_in[1];
    const int*   ridx = (const int*)d_in[2];
    const float* Eaa  = (const float*)d_in[3];
    const float* Epos = (const float*)d_in[4];
    const float* Ech  = (const float*)d_in[5];
    const float* Ecp  = (const float*)d_in[6];
    const float* Erp  = (const float*)d_in[7];
    const float* Wp   = (const float*)d_in[8];
    const float* bp   = (const float*)d_in[9];
    const float* lnw  = (const float*)d_in[10];
    const float* lnb  = (const float*)d_in[11];

    float* out   = (float*)d_out;
    float* s_out = out;
    float* zout  = out + L * CS;

    char* ws = (char*)d_ws;
    f16_t* u2   = (f16_t*)ws;                 // 256 KB, chunk-major
    f16_t* w3c  = (f16_t*)(ws + 262144);      // 64 KB, chunk-major
    float* zrow = (float*)(ws + 327680);      // 256 KB
    float* zcol = (float*)(ws + 589824);      // 256 KB
    float* tab  = (float*)(ws + 851968);      // 132 KB

    hipLaunchKernelGGL(k_prep, dim3(L), dim3(256), 0, stream,
                       seq, cid, ridx, Eaa, Epos, Ech, lnw, lnb, Wp, bp,
                       Ecp, Erp, s_out, u2, zrow, zcol, w3c, tab);
    hipLaunchKernelGGL(k_pair, dim3(16, 64), dim3(512), 0, stream,
                       u2, w3c, zrow, zcol, tab, cid, ridx, zout);
}

// Round 3
// 183.334 us; speedup vs baseline: 1.1966x; 1.0572x over previous
//
#include <hip/hip_runtime.h>
#include <hip/hip_bf16.h>

#define L 512
#define CS 256
#define CZ 128
#define LN_EPS 1e-5f

typedef _Float16 f16_t;
typedef f16_t f16x8 __attribute__((ext_vector_type(8)));
typedef float f32x4 __attribute__((ext_vector_type(4)));

// ---- Kernel PREP -----------------------------------------------------------
// Per-block (i = blockIdx.x): embed + LN -> s_out, u2 (CHUNK-MAJOR f16:
// u2[c>>3][i][c&7]), zrow = u@W1 + b, zcol = u@W2.
// Spare duties: blocks 0..127 build w3c (chunk-major W3^T f16), blocks
// 128..391 build tab[cp*66+rp] = Ecp[cp] + Erp[rp].
__global__ __launch_bounds__(256) void k_prep(
    const int* __restrict__ seq, const int* __restrict__ cid,
    const int* __restrict__ ridx,
    const float* __restrict__ Eaa, const float* __restrict__ Epos,
    const float* __restrict__ Ech, const float* __restrict__ lnw,
    const float* __restrict__ lnb, const float* __restrict__ Wp,
    const float* __restrict__ bp, const float* __restrict__ Ecp,
    const float* __restrict__ Erp,
    float* __restrict__ s_out, f16_t* __restrict__ u2,
    float* __restrict__ zrow, float* __restrict__ zcol,
    f16_t* __restrict__ w3c, float* __restrict__ tab)
{
    __shared__ float su[CS];
    __shared__ float red[8];
    const int i = blockIdx.x;
    const int c = threadIdx.x;

    if (i < 128) {
        w3c[(c >> 3) * (CZ * 8) + i * 8 + (c & 7)] = (f16_t)Wp[(2 * CS + c) * CZ + i];
    } else if (i < 128 + 264) {
        const int b2 = i - 128;
        if (c < CZ)
            tab[b2 * CZ + c] = Ecp[(b2 / 66) * CZ + c] + Erp[(b2 % 66) * CZ + c];
    }

    const int sq = seq[i], ri = ridx[i], ci = cid[i];
    const float v = Eaa[sq * CS + c] + Epos[ri * CS + c] + Ech[ci * CS + c];
    s_out[i * CS + c] = v;

    float s1 = v, s2 = v * v;
    #pragma unroll
    for (int o = 32; o > 0; o >>= 1) {
        s1 += __shfl_down(s1, o, 64);
        s2 += __shfl_down(s2, o, 64);
    }
    const int wv = c >> 6, lane = c & 63;
    if (lane == 0) { red[wv * 2] = s1; red[wv * 2 + 1] = s2; }
    __syncthreads();
    const float S  = red[0] + red[2] + red[4] + red[6];
    const float SS = red[1] + red[3] + red[5] + red[7];
    const float mu  = S * (1.0f / CS);
    const float var = SS * (1.0f / CS) - mu * mu;
    const float rs  = rsqrtf(var + LN_EPS);
    const float u   = (v - mu) * rs * lnw[c] + lnb[c];
    u2[(c >> 3) * (L * 8) + i * 8 + (c & 7)] = (f16_t)u;
    su[c] = u;
    __syncthreads();

    const int z = c & 127;
    const int half = c >> 7;  // 0 -> zrow(W1), 1 -> zcol(W2)
    const float* W = Wp + half * CS * CZ + z;
    float a0 = 0, a1 = 0, a2 = 0, a3 = 0;
    #pragma unroll 8
    for (int cc = 0; cc < CS; cc += 4) {
        a0 += su[cc + 0] * W[(cc + 0) * CZ];
        a1 += su[cc + 1] * W[(cc + 1) * CZ];
        a2 += su[cc + 2] * W[(cc + 2) * CZ];
        a3 += su[cc + 3] * W[(cc + 3) * CZ];
    }
    const float acc = (a0 + a1) + (a2 + a3);
    if (half) zcol[i * CZ + z] = acc;
    else      zrow[i * CZ + z] = acc + bp[z];
}

// ---- Kernel PAIR (v4: 2-pass z-split for occupancy + store overlap) --------
// v3 residue: acc[4][4]=64 VGPR + operands -> >128 VGPR -> only 2 waves/SIMD
// at (512,2), and ONE store burst at the end serialized after the whole MFMA
// phase. v4: each wave's 64z is processed in 2 passes of 32z, each with its
// own half-epilogue. acc 64->32 VGPR, live ~100 -> fits the 128-VGPR cap of
// (512,4) -> 4 waves/SIMD (2 blocks/CU). Pass-1 stores are fire-and-forget:
// they drain under pass-2's ds_read+MFMA chain (rolled pass loop keeps reg
// pressure down; stores need no waitcnt). Epilogue index math hoisted before
// the barrier. Costs of the split (2x B-products ~2K VALU cyc/SIMD, 2x ds
// reads ~15K cyc/CU) stay under the 52K-cyc/CU store floor.
// k32 loop unroll-capped at 2 so the compiler can't R1-style hoist all
// A-loads into registers.
__global__ __launch_bounds__(512, 4) void k_pair(
    const f16_t* __restrict__ u2, const f16_t* __restrict__ w3c,
    const float* __restrict__ zrow, const float* __restrict__ zcol,
    const float* __restrict__ tab,
    const int* __restrict__ cid, const int* __restrict__ ridx,
    float* __restrict__ zout)
{
    __shared__ f16_t lds[(1024 + 256) * 8];  // u_j tile (16KB) + u_i tile (4KB)
    f16x8* lj = (f16x8*)lds;
    f16x8* li = ((f16x8*)lds) + 1024;

    const int t = threadIdx.x;
    const int lane = t & 63, wave = t >> 6;
    const int m = lane & 15, q = lane >> 4;
    const int j0 = blockIdx.x * 32, i0 = blockIdx.y * 8;
    const int jh = wave & 1;          // j-half: 16 j's
    const int ih = (wave >> 1) & 1;   // i-half: 4 i's
    const int zh = wave >> 2;         // z-half: 64 z's (2 passes of 32)
    const int jm = j0 + jh * 16 + m;
    const int ib = ih * 4;            // local i base
    const int zb = zh * 64;

    const f16x8* pu = (const f16x8*)u2;      // [32 chunks][512 rows]
    const f16x8* pw = (const f16x8*)w3c;     // [32 chunks][128 z]

    // stage LDS tiles (contiguous src + dst; R0-verified conflict-free)
    if (t < 256) li[t] = pu[(t >> 3) * L + i0 + (t & 7)];   // t = ch*8 + ii
    #pragma unroll
    for (int rep = 0; rep < 2; ++rep) {
        const int un = rep * 512 + t;                       // un = ch*32 + jj
        lj[un] = pu[(un >> 5) * L + j0 + (un & 31)];
    }

    // epilogue index math, hoisted (independent of LDS)
    const int cj = cid[jm], rj = ridx[jm];
    int xx[4];
    #pragma unroll
    for (int ii = 0; ii < 4; ++ii) {
        const int i = i0 + ib + ii;
        const int ci = cid[i], ri = ridx[i];
        int d = ri - rj; d = d < -32 ? -32 : (d > 32 ? 32 : d);
        xx[ii] = ((ci * 2 + cj) * 66) + ((ci == cj) ? (d + 32) : 65);
    }

    __syncthreads();

    #pragma unroll 1   // rolled: keeps regs at 1-pass live set; stores of
    for (int pass = 0; pass < 2; ++pass) {   // pass 0 drain under pass 1
        const int z0 = zb + pass * 32;

        f32x4 acc[4][2];  // [ii][zt]
        #pragma unroll
        for (int ii = 0; ii < 4; ++ii) {
            acc[ii][0] = (f32x4){0.f, 0.f, 0.f, 0.f};
            acc[ii][1] = (f32x4){0.f, 0.f, 0.f, 0.f};
        }

        #pragma unroll 2
        for (int k32 = 0; k32 < 8; ++k32) {
            const int cb = k32 * 4 + q;               // c-chunk index
            const f16x8 A0 = pw[cb * CZ + z0 + m];        // W3^T, L2-resident
            const f16x8 A1 = pw[cb * CZ + z0 + 16 + m];
            const f16x8 ujv = lj[cb * 32 + jh * 16 + m];  // conflict-free b128
            #pragma unroll
            for (int ii = 0; ii < 4; ++ii) {
                const f16x8 B = li[cb * 8 + ib + ii] * ujv; // bcast + 4 v_pk
                acc[ii][0] = __builtin_amdgcn_mfma_f32_16x16x32_f16(A0, B, acc[ii][0], 0, 0, 0);
                acc[ii][1] = __builtin_amdgcn_mfma_f32_16x16x32_f16(A1, B, acc[ii][1], 0, 0, 0);
            }
        }

        // half-epilogue: z = z0 + zt*16 + q*4 + r
        const int zo0 = z0 + q * 4;
        const int zo1 = z0 + 16 + q * 4;
        const f32x4 ZC0 = *(const f32x4*)&zcol[jm * CZ + zo0];
        const f32x4 ZC1 = *(const f32x4*)&zcol[jm * CZ + zo1];
        #pragma unroll
        for (int ii = 0; ii < 4; ++ii) {
            const int i = i0 + ib + ii;
            float* r_o = zout + ((size_t)i * L + jm) * CZ;
            const f32x4 zr0 = *(const f32x4*)&zrow[i * CZ + zo0];
            const f32x4 zr1 = *(const f32x4*)&zrow[i * CZ + zo1];
            const f32x4 tb0 = *(const f32x4*)&tab[xx[ii] * CZ + zo0];
            const f32x4 tb1 = *(const f32x4*)&tab[xx[ii] * CZ + zo1];
            *(f32x4*)(r_o + zo0) = acc[ii][0] + zr0 + ZC0 + tb0;
            *(f32x4*)(r_o + zo1) = acc[ii][1] + zr1 + ZC1 + tb1;
        }
    }
}

extern "C" void kernel_launch(void* const* d_in, const int* in_sizes, int n_in,
                              void* d_out, int out_size, void* d_ws, size_t ws_size,
                              hipStream_t stream) {
    const int*   seq  = (const int*)d_in[0];
    const int*   cid  = (const int*)d_in[1];
    const int*   ridx = (const int*)d_in[2];
    const float* Eaa  = (const float*)d_in[3];
    const float* Epos = (const float*)d_in[4];
    const float* Ech  = (const float*)d_in[5];
    const float* Ecp  = (const float*)d_in[6];
    const float* Erp  = (const float*)d_in[7];
    const float* Wp   = (const float*)d_in[8];
    const float* bp   = (const float*)d_in[9];
    const float* lnw  = (const float*)d_in[10];
    const float* lnb  = (const float*)d_in[11];

    float* out   = (float*)d_out;
    float* s_out = out;
    float* zout  = out + L * CS;

    char* ws = (char*)d_ws;
    f16_t* u2   = (f16_t*)ws;                 // 256 KB, chunk-major
    f16_t* w3c  = (f16_t*)(ws + 262144);      // 64 KB, chunk-major
    float* zrow = (float*)(ws + 327680);      // 256 KB
    float* zcol = (float*)(ws + 589824);      // 256 KB
    float* tab  = (float*)(ws + 851968);      // 132 KB

    hipLaunchKernelGGL(k_prep, dim3(L), dim3(256), 0, stream,
                       seq, cid, ridx, Eaa, Epos, Ech, lnw, lnb, Wp, bp,
                       Ecp, Erp, s_out, u2, zrow, zcol, w3c, tab);
    hipLaunchKernelGGL(k_pair, dim3(16, 64), dim3(512), 0, stream,
                       u2, w3c, zrow, zcol, tab, cid, ridx, zout);
}